// Round 1
// baseline (782.820 us; speedup 1.0000x reference)
//
#include <hip/hip_runtime.h>
#include <hip/hip_bf16.h>

typedef short bf16x8 __attribute__((ext_vector_type(8)));
typedef float f32x4 __attribute__((ext_vector_type(4)));

#define LOG2E 1.4426950408889634f
#define QKV_E ((size_t)24*4096*64)

__device__ __forceinline__ float bfu2f(unsigned short u) {
  unsigned v = ((unsigned)u) << 16;
  return __builtin_bit_cast(float, v);
}
__device__ __forceinline__ unsigned short f2bfu(float f) {
  unsigned u = __builtin_bit_cast(unsigned, f);
  u += 0x7fffu + ((u >> 16) & 1u);
  return (unsigned short)(u >> 16);
}

// ---------------- RMSNorm: x fp32 [8192][768] -> xn bf16 ----------------
__global__ __launch_bounds__(256) void rmsnorm_k(const float* __restrict__ x,
    const float* __restrict__ w, ushort* __restrict__ xn) {
  int row = blockIdx.x, t = threadIdx.x;
  const float* xr = x + (size_t)row * 768;
  float v0 = xr[t], v1 = xr[t + 256], v2 = xr[t + 512];
  float ss = v0 * v0 + v1 * v1 + v2 * v2;
#pragma unroll
  for (int m = 32; m >= 1; m >>= 1) ss += __shfl_xor(ss, m, 64);
  __shared__ float part[4];
  if ((t & 63) == 0) part[t >> 6] = ss;
  __syncthreads();
  float tot = part[0] + part[1] + part[2] + part[3];
  float rr = rsqrtf(tot * (1.0f / 768.0f) + 1e-6f);
  ushort* xo = xn + (size_t)row * 768;
  xo[t]       = f2bfu(v0 * rr * w[t]);
  xo[t + 256] = f2bfu(v1 * rr * w[t + 256]);
  xo[t + 512] = f2bfu(v2 * rr * w[t + 512]);
}

// ------------- transpose + fp32->bf16: in [R][C] -> out [C][R] -------------
__global__ __launch_bounds__(256) void tcvt_k(const float* __restrict__ in,
    ushort* __restrict__ out, int R, int C) {
  __shared__ float tile[32][33];
  int c0 = blockIdx.x * 32, r0 = blockIdx.y * 32;
  int t = threadIdx.x;
  int j = t & 31, i0 = t >> 5;
#pragma unroll
  for (int i = i0; i < 32; i += 8) tile[i][j] = in[(size_t)(r0 + i) * C + c0 + j];
  __syncthreads();
#pragma unroll
  for (int i = i0; i < 32; i += 8) out[(size_t)(c0 + i) * R + r0 + j] = f2bfu(tile[j][i]);
}

// ---------------- shared GEMM core: C[128][128] += A[128xK] * Bt[128xK]^T --
// A: [M][K] bf16 row-major; Bt: [N][K] bf16 row-major (i.e. B transposed).
// LDS tiles 128x64 bf16, XOR-swizzled chunks: chunk c at row r stored at c^(r&7).
__device__ __forceinline__ void gemm_core(const ushort* __restrict__ A,
    const ushort* __restrict__ Bt, int K, int mBase, int nBase,
    ushort* As, ushort* Bs, f32x4 acc[4][4]) {
  const int t = threadIdx.x;
  const int lane = t & 63, w = t >> 6;
  const int wr = w >> 1, wc = w & 1;
  int r_[4], c_[4];
#pragma unroll
  for (int j = 0; j < 4; ++j) {
    int ch = t + 256 * j;
    r_[j] = ch >> 3;
    c_[j] = ch & 7;
  }
  int4 ra[4], rb[4];
#pragma unroll
  for (int j = 0; j < 4; ++j) {
    ra[j] = *(const int4*)(A  + (size_t)(mBase + r_[j]) * K + c_[j] * 8);
    rb[j] = *(const int4*)(Bt + (size_t)(nBase + r_[j]) * K + c_[j] * 8);
  }
  for (int k0 = 64;; k0 += 64) {
    __syncthreads();
#pragma unroll
    for (int j = 0; j < 4; ++j) {
      *(int4*)(As + r_[j] * 64 + ((c_[j] ^ (r_[j] & 7)) << 3)) = ra[j];
      *(int4*)(Bs + r_[j] * 64 + ((c_[j] ^ (r_[j] & 7)) << 3)) = rb[j];
    }
    bool more = k0 < K;
    if (more) {
#pragma unroll
      for (int j = 0; j < 4; ++j) {
        ra[j] = *(const int4*)(A  + (size_t)(mBase + r_[j]) * K + k0 + c_[j] * 8);
        rb[j] = *(const int4*)(Bt + (size_t)(nBase + r_[j]) * K + k0 + c_[j] * 8);
      }
    }
    __syncthreads();
#pragma unroll
    for (int kk = 0; kk < 2; ++kk) {
      bf16x8 af[4], bff[4];
#pragma unroll
      for (int m = 0; m < 4; ++m) {
        int row = wr * 64 + m * 16 + (lane & 15);
        int c = kk * 4 + (lane >> 4);
        af[m] = *(const bf16x8*)(As + row * 64 + ((c ^ (row & 7)) << 3));
      }
#pragma unroll
      for (int n = 0; n < 4; ++n) {
        int row = wc * 64 + n * 16 + (lane & 15);
        int c = kk * 4 + (lane >> 4);
        bff[n] = *(const bf16x8*)(Bs + row * 64 + ((c ^ (row & 7)) << 3));
      }
#pragma unroll
      for (int m = 0; m < 4; ++m)
#pragma unroll
        for (int n = 0; n < 4; ++n)
          acc[m][n] = __builtin_amdgcn_mfma_f32_16x16x32_bf16(af[m], bff[n], acc[m][n], 0, 0, 0);
    }
    if (!more) break;
  }
}

// ---------------- GEMM1: xn @ W_in + b_in -> qkv scatter + gelu(ff) -------
__global__ __launch_bounds__(256) void gemm1_k(const ushort* __restrict__ A,
    const ushort* __restrict__ Bt, const float* __restrict__ bias,
    ushort* __restrict__ qraw, ushort* __restrict__ comb) {
  __shared__ __align__(16) ushort As[128 * 64];
  __shared__ __align__(16) ushort Bs[128 * 64];
  f32x4 acc[4][4];
  f32x4 z = {0.f, 0.f, 0.f, 0.f};
#pragma unroll
  for (int m = 0; m < 4; ++m)
#pragma unroll
    for (int n = 0; n < 4; ++n) acc[m][n] = z;
  int mBase = blockIdx.y * 128, nBase = blockIdx.x * 128;
  gemm_core(A, Bt, 768, mBase, nBase, As, Bs, acc);
  int t = threadIdx.x, lane = t & 63, w = t >> 6, wr = w >> 1, wc = w & 1;
  int col0 = nBase + wc * 64 + (lane & 15);
  int row0 = mBase + wr * 64 + ((lane >> 4) << 2);
#pragma unroll
  for (int n = 0; n < 4; ++n) {
    int col = col0 + n * 16;
    float bv = bias[col];
    bool isff = (col >= 2304);
    int qi = 0, h = 0, d = 0;
    if (!isff) { qi = col / 768; int rem = col - qi * 768; h = rem >> 6; d = rem & 63; }
    int fcol = col - 2304 + 768;
#pragma unroll
    for (int m = 0; m < 4; ++m) {
#pragma unroll
      for (int r = 0; r < 4; ++r) {
        int row = row0 + m * 16 + r;
        float v = acc[m][n][r] + bv;
        if (isff) {
          float g = 0.5f * v * (1.0f + erff(v * 0.70710678118f));
          comb[(size_t)row * 3840 + fcol] = f2bfu(g);
        } else {
          int b = row >> 12, s = row & 4095;
          qraw[(size_t)((qi * 24 + b * 12 + h) * 4096 + s) * 64 + d] = f2bfu(v);
        }
      }
    }
  }
}

// ---------------- GEMM2: comb @ W_out + b_out -> fp32 out ----------------
__global__ __launch_bounds__(256) void gemm2_k(const ushort* __restrict__ A,
    const ushort* __restrict__ Bt, const float* __restrict__ bias,
    float* __restrict__ out) {
  __shared__ __align__(16) ushort As[128 * 64];
  __shared__ __align__(16) ushort Bs[128 * 64];
  f32x4 acc[4][4];
  f32x4 z = {0.f, 0.f, 0.f, 0.f};
#pragma unroll
  for (int m = 0; m < 4; ++m)
#pragma unroll
    for (int n = 0; n < 4; ++n) acc[m][n] = z;
  int mBase = blockIdx.y * 128, nBase = blockIdx.x * 128;
  gemm_core(A, Bt, 3840, mBase, nBase, As, Bs, acc);
  int t = threadIdx.x, lane = t & 63, w = t >> 6, wr = w >> 1, wc = w & 1;
  int col0 = nBase + wc * 64 + (lane & 15);
  int row0 = mBase + wr * 64 + ((lane >> 4) << 2);
#pragma unroll
  for (int n = 0; n < 4; ++n) {
    int col = col0 + n * 16;
    float bv = bias[col];
#pragma unroll
    for (int m = 0; m < 4; ++m)
#pragma unroll
      for (int r = 0; r < 4; ++r) {
        int row = row0 + m * 16 + r;
        out[(size_t)row * 768 + col] = acc[m][n][r] + bv;
      }
  }
}

// ---------------- RoPE on q,k (q also scaled by 1/8) ----------------------
__global__ __launch_bounds__(256) void rope_k(const ushort* __restrict__ qraw,
    const float* __restrict__ sn, const float* __restrict__ cs,
    ushort* __restrict__ qo, ushort* __restrict__ ko) {
  int idx = blockIdx.x * 256 + threadIdx.x;  // < 24*4096*32
  int pr = idx & 31;
  int rest = idx >> 5;
  int s = rest & 4095;
  int soff = (s << 6) + (pr << 1);
  float sv = sn[soff], cv = cs[soff];
  size_t off = ((size_t)rest << 6) + (pr << 1);
  ushort2 qv = *(const ushort2*)(qraw + off);
  ushort2 kv = *(const ushort2*)(qraw + QKV_E + off);
  float q0 = bfu2f(qv.x), q1 = bfu2f(qv.y);
  float k0 = bfu2f(kv.x), k1 = bfu2f(kv.y);
  ushort2 oq, ok;
  oq.x = f2bfu((q0 * cv - q1 * sv) * 0.125f);
  oq.y = f2bfu((q1 * cv + q0 * sv) * 0.125f);
  ok.x = f2bfu(k0 * cv - k1 * sv);
  ok.y = f2bfu(k1 * cv + k0 * sv);
  *(ushort2*)(qo + off) = oq;
  *(ushort2*)(ko + off) = ok;
}

// ---------------- V transpose: [bh][s][64] -> [bh][64][s] -----------------
__global__ __launch_bounds__(256) void vtr_k(const ushort* __restrict__ vraw,
    ushort* __restrict__ vt) {
  __shared__ __align__(16) ushort tile[64][72];
  int bh = blockIdx.y;
  int s0 = blockIdx.x * 64;
  int t = threadIdx.x;
  int r = t >> 2, c0 = (t & 3) * 16;
  const ushort* src = vraw + ((size_t)(bh * 4096 + s0 + r)) * 64 + c0;
  *(int4*)(&tile[r][c0])     = *(const int4*)(src);
  *(int4*)(&tile[r][c0 + 8]) = *(const int4*)(src + 8);
  __syncthreads();
  ushort* dst = vt + ((size_t)(bh * 64 + r)) * 4096 + s0 + c0;
#pragma unroll
  for (int h = 0; h < 2; ++h) {
    int w0 = tile[c0 + 8 * h + 0][r] | (tile[c0 + 8 * h + 1][r] << 16);
    int w1 = tile[c0 + 8 * h + 2][r] | (tile[c0 + 8 * h + 3][r] << 16);
    int w2 = tile[c0 + 8 * h + 4][r] | (tile[c0 + 8 * h + 5][r] << 16);
    int w3 = tile[c0 + 8 * h + 6][r] | (tile[c0 + 8 * h + 7][r] << 16);
    int4 o4; o4.x = w0; o4.y = w1; o4.z = w2; o4.w = w3;
    *(int4*)(dst + 8 * h) = o4;
  }
}

// ---------------- windowed attention (flash-style, window 512) ------------
// q,k: [bh][s][64]; vt: [bh][64][s]; writes comb[:, 0:768]
__global__ __launch_bounds__(256) void attn_k(const ushort* __restrict__ qb,
    const ushort* __restrict__ kb, const ushort* __restrict__ vt,
    ushort* __restrict__ comb) {
  __shared__ __align__(16) ushort Ks[128 * 64];
  __shared__ __align__(16) ushort Vs[64 * 128];
  __shared__ __align__(16) ushort Ps[4][32 * 128];
  int qt = blockIdx.x, bh = blockIdx.y;
  int t = threadIdx.x, lane = t & 63, w = t >> 6;
  int qlo = qt * 128;
  const size_t base = (size_t)bh * 4096 * 64;
  bf16x8 qa[2][2];
#pragma unroll
  for (int m = 0; m < 2; ++m)
#pragma unroll
    for (int kk = 0; kk < 2; ++kk) {
      int row = qlo + w * 32 + m * 16 + (lane & 15);
      qa[m][kk] = *(const bf16x8*)(qb + base + (size_t)row * 64 + kk * 32 + ((lane >> 4) << 3));
    }
  f32x4 z = {0.f, 0.f, 0.f, 0.f};
  f32x4 o[2][4];
  float m_run[2][4], l_run[2][4];
#pragma unroll
  for (int m = 0; m < 2; ++m)
#pragma unroll
    for (int r = 0; r < 4; ++r) { m_run[m][r] = -1e30f; l_run[m][r] = 0.f; }
#pragma unroll
  for (int m = 0; m < 2; ++m)
#pragma unroll
    for (int df = 0; df < 4; ++df) o[m][df] = z;
  ushort* pw = &Ps[w][0];
  int t0 = qt >= 4 ? qt - 4 : 0;
  for (int kt = t0; kt <= qt; ++kt) {
    int k0 = kt * 128;
    __syncthreads();
#pragma unroll
    for (int j = 0; j < 4; ++j) {
      int ch = t + 256 * j;
      int key = ch >> 3, c = ch & 7;
      *(int4*)(Ks + key * 64 + ((c ^ (key & 7)) << 3)) =
          *(const int4*)(kb + base + (size_t)(k0 + key) * 64 + c * 8);
      int dd = ch >> 4, c2 = ch & 15;
      *(int4*)(Vs + dd * 128 + ((c2 ^ (dd & 15)) << 3)) =
          *(const int4*)(vt + base + (size_t)dd * 4096 + k0 + c2 * 8);
    }
    __syncthreads();
    f32x4 s[2][8];
#pragma unroll
    for (int m = 0; m < 2; ++m)
#pragma unroll
      for (int n = 0; n < 8; ++n) s[m][n] = z;
#pragma unroll
    for (int kk = 0; kk < 2; ++kk) {
      bf16x8 kf[8];
#pragma unroll
      for (int n = 0; n < 8; ++n) {
        int key = n * 16 + (lane & 15);
        int c = kk * 4 + (lane >> 4);
        kf[n] = *(const bf16x8*)(Ks + key * 64 + ((c ^ (key & 7)) << 3));
      }
#pragma unroll
      for (int m = 0; m < 2; ++m)
#pragma unroll
        for (int n = 0; n < 8; ++n)
          s[m][n] = __builtin_amdgcn_mfma_f32_16x16x32_bf16(qa[m][kk], kf[n], s[m][n], 0, 0, 0);
    }
    // mask + online softmax (rows owned per (m,reg), 16-lane col groups)
#pragma unroll
    for (int m = 0; m < 2; ++m) {
#pragma unroll
      for (int r = 0; r < 4; ++r) {
        int qrow = qlo + w * 32 + m * 16 + ((lane >> 4) << 2) + r;
        float mx = -3e38f;
#pragma unroll
        for (int n = 0; n < 8; ++n) {
          int krow = k0 + n * 16 + (lane & 15);
          if ((unsigned)(qrow - krow) >= 512u) s[m][n][r] = -3e38f;
          mx = fmaxf(mx, s[m][n][r]);
        }
        mx = fmaxf(mx, __shfl_xor(mx, 1, 64));
        mx = fmaxf(mx, __shfl_xor(mx, 2, 64));
        mx = fmaxf(mx, __shfl_xor(mx, 4, 64));
        mx = fmaxf(mx, __shfl_xor(mx, 8, 64));
        float mo = m_run[m][r];
        float mn = fmaxf(mo, mx);
        float sc = exp2f((mo - mn) * LOG2E);
        m_run[m][r] = mn;
        l_run[m][r] *= sc;
#pragma unroll
        for (int df = 0; df < 4; ++df) o[m][df][r] *= sc;
        float ls = 0.f;
#pragma unroll
        for (int n = 0; n < 8; ++n) {
          float p = exp2f((s[m][n][r] - mn) * LOG2E);
          s[m][n][r] = p;
          ls += p;
        }
        ls += __shfl_xor(ls, 1, 64);
        ls += __shfl_xor(ls, 2, 64);
        ls += __shfl_xor(ls, 4, 64);
        ls += __shfl_xor(ls, 8, 64);
        l_run[m][r] += ls;
      }
    }
    // P -> LDS (bf16, chunk-swizzled)
#pragma unroll
    for (int m = 0; m < 2; ++m)
#pragma unroll
      for (int n = 0; n < 8; ++n)
#pragma unroll
        for (int r = 0; r < 4; ++r) {
          int prow = m * 16 + ((lane >> 4) << 2) + r;
          int pcol = n * 16 + (lane & 15);
          int c = pcol >> 3;
          pw[prow * 128 + ((c ^ (prow & 7)) << 3) + (pcol & 7)] = f2bfu(s[m][n][r]);
        }
    __syncthreads();
    // PV
#pragma unroll
    for (int kk2 = 0; kk2 < 4; ++kk2) {
      bf16x8 pa[2];
#pragma unroll
      for (int m = 0; m < 2; ++m) {
        int prow = m * 16 + (lane & 15);
        int c = kk2 * 4 + (lane >> 4);
        pa[m] = *(const bf16x8*)(pw + prow * 128 + ((c ^ (prow & 7)) << 3));
      }
#pragma unroll
      for (int df = 0; df < 4; ++df) {
        int dim = df * 16 + (lane & 15);
        int c = kk2 * 4 + (lane >> 4);
        bf16x8 vf = *(const bf16x8*)(Vs + dim * 128 + ((c ^ (dim & 15)) << 3));
#pragma unroll
        for (int m = 0; m < 2; ++m)
          o[m][df] = __builtin_amdgcn_mfma_f32_16x16x32_bf16(pa[m], vf, o[m][df], 0, 0, 0);
      }
    }
  }
  int b = bh / 12, h = bh - (bh / 12) * 12;
#pragma unroll
  for (int m = 0; m < 2; ++m)
#pragma unroll
    for (int df = 0; df < 4; ++df)
#pragma unroll
      for (int r = 0; r < 4; ++r) {
        int row = qlo + w * 32 + m * 16 + ((lane >> 4) << 2) + r;
        int dim = df * 16 + (lane & 15);
        float val = o[m][df][r] / l_run[m][r];
        comb[(size_t)(b * 4096 + row) * 3840 + h * 64 + dim] = f2bfu(val);
      }
}

extern "C" void kernel_launch(void* const* d_in, const int* in_sizes, int n_in,
                              void* d_out, int out_size, void* d_ws, size_t ws_size,
                              hipStream_t stream) {
  (void)in_sizes; (void)n_in; (void)out_size; (void)ws_size;
  const float* x      = (const float*)d_in[0];
  const float* sin_t  = (const float*)d_in[1];
  const float* cos_t  = (const float*)d_in[2];
  const float* w_norm = (const float*)d_in[3];
  const float* W_in   = (const float*)d_in[4];
  const float* b_in   = (const float*)d_in[5];
  const float* W_out  = (const float*)d_in[6];
  const float* b_out  = (const float*)d_in[7];
  float* out = (float*)d_out;

  const size_t XN_E  = (size_t)8192 * 768;
  const size_t WIT_E = (size_t)5376 * 768;
  const size_t WOT_E = (size_t)768 * 3840;
  ushort* xn      = (ushort*)d_ws;
  ushort* w_in_t  = xn + XN_E;
  ushort* w_out_t = w_in_t + WIT_E;
  ushort* qraw    = w_out_t + WOT_E;      // [3][24][4096][64]
  ushort* qbuf    = qraw + 3 * QKV_E;
  ushort* kbuf    = qbuf + QKV_E;
  ushort* vt      = kbuf + QKV_E;         // [24][64][4096]
  ushort* comb    = vt + QKV_E;           // [8192][3840]

  rmsnorm_k<<<dim3(8192), dim3(256), 0, stream>>>(x, w_norm, xn);
  tcvt_k<<<dim3(5376 / 32, 768 / 32), dim3(256), 0, stream>>>(W_in, w_in_t, 768, 5376);
  tcvt_k<<<dim3(768 / 32, 3840 / 32), dim3(256), 0, stream>>>(W_out, w_out_t, 3840, 768);
  gemm1_k<<<dim3(42, 64), dim3(256), 0, stream>>>(xn, w_in_t, b_in, qraw, comb);
  rope_k<<<dim3(12288), dim3(256), 0, stream>>>(qraw, sin_t, cos_t, qbuf, kbuf);
  vtr_k<<<dim3(64, 24), dim3(256), 0, stream>>>(qraw + 2 * QKV_E, vt);
  attn_k<<<dim3(32, 24), dim3(256), 0, stream>>>(qbuf, kbuf, vt, comb);
  gemm2_k<<<dim3(6, 64), dim3(256), 0, stream>>>(comb, w_out_t, b_out, out);
}

// Round 2
// 300.916 us; speedup vs baseline: 2.6015x; 2.6015x over previous
//
#include <hip/hip_runtime.h>
#include <hip/hip_bf16.h>

typedef short bf16x8 __attribute__((ext_vector_type(8)));
typedef float f32x4 __attribute__((ext_vector_type(4)));

#define LOG2E 1.4426950408889634f
#define QKV_E ((size_t)24*4096*64)

__device__ __forceinline__ float bfu2f(unsigned short u) {
  unsigned v = ((unsigned)u) << 16;
  return __builtin_bit_cast(float, v);
}
__device__ __forceinline__ unsigned short f2bfu(float f) {
  unsigned u = __builtin_bit_cast(unsigned, f);
  u += 0x7fffu + ((u >> 16) & 1u);
  return (unsigned short)(u >> 16);
}
__device__ __forceinline__ float gelu_f(float v) {
  float a = fabsf(v) * 0.70710678118654752f;
  float t = 1.0f / (1.0f + 0.3275911f * a);
  float poly = ((((1.061405429f * t - 1.453152027f) * t + 1.421413741f) * t
                 - 0.284496736f) * t + 0.254829592f) * t;
  float erfa = 1.0f - poly * __expf(-a * a);
  float erfv = v >= 0.0f ? erfa : -erfa;
  return 0.5f * v * (1.0f + erfv);
}
__device__ __forceinline__ void gl_lds16(const ushort* g, ushort* l) {
  __builtin_amdgcn_global_load_lds(
      (const __attribute__((address_space(1))) unsigned int*)(const void*)g,
      (__attribute__((address_space(3))) unsigned int*)(void*)l, 16, 0, 0);
}

// ---------------- RMSNorm: x fp32 [8192][768] -> xn bf16 ----------------
__global__ __launch_bounds__(256) void rmsnorm_k(const float* __restrict__ x,
    const float* __restrict__ w, ushort* __restrict__ xn) {
  int row = blockIdx.x, t = threadIdx.x;
  const float* xr = x + (size_t)row * 768;
  float v0 = xr[t], v1 = xr[t + 256], v2 = xr[t + 512];
  float ss = v0 * v0 + v1 * v1 + v2 * v2;
#pragma unroll
  for (int m = 32; m >= 1; m >>= 1) ss += __shfl_xor(ss, m, 64);
  __shared__ float part[4];
  if ((t & 63) == 0) part[t >> 6] = ss;
  __syncthreads();
  float tot = part[0] + part[1] + part[2] + part[3];
  float rr = rsqrtf(tot * (1.0f / 768.0f) + 1e-6f);
  ushort* xo = xn + (size_t)row * 768;
  xo[t]       = f2bfu(v0 * rr * w[t]);
  xo[t + 256] = f2bfu(v1 * rr * w[t + 256]);
  xo[t + 512] = f2bfu(v2 * rr * w[t + 512]);
}

// ------------- transpose + fp32->bf16: in [R][C] -> out [C][R] -------------
__global__ __launch_bounds__(256) void tcvt_k(const float* __restrict__ in,
    ushort* __restrict__ out, int R, int C) {
  __shared__ float tile[32][33];
  int c0 = blockIdx.x * 32, r0 = blockIdx.y * 32;
  int t = threadIdx.x;
  int j = t & 31, i0 = t >> 5;
#pragma unroll
  for (int i = i0; i < 32; i += 8) tile[i][j] = in[(size_t)(r0 + i) * C + c0 + j];
  __syncthreads();
#pragma unroll
  for (int i = i0; i < 32; i += 8) out[(size_t)(c0 + i) * R + r0 + j] = f2bfu(tile[j][i]);
}

// ---- GEMM core, global_load_lds staging, SWAPPED mfma (D = C^T mapping) ---
// A: [M][lda] bf16; Bt: [N][lda] bf16 (B transposed). K range [0, kLen).
// acc[m][n] reg r -> (Mrow = mBase+wr*64+m*16+(lane&15),
//                     Ncol = nBase+wc*64+n*16+(lane>>4)*4+r)
__device__ __forceinline__ void gemm_core(const ushort* __restrict__ A,
    const ushort* __restrict__ Bt, int lda, int kLen, int mBase, int nBase,
    ushort* As, ushort* Bs, f32x4 acc[4][4]) {
  const int t = threadIdx.x;
  const int lane = t & 63, w = t >> 6;
  const int wr = w >> 1, wc = w & 1;
  const ushort* ga[4]; const ushort* gb[4];
  ushort* la[4]; ushort* lb[4];
#pragma unroll
  for (int j = 0; j < 4; ++j) {
    int r = w * 32 + j * 8 + (lane >> 3);
    int gc = (lane & 7) ^ (r & 7);
    ga[j] = A  + (size_t)(mBase + r) * lda + gc * 8;
    gb[j] = Bt + (size_t)(nBase + r) * lda + gc * 8;
    la[j] = As + (w * 32 + j * 8) * 64;
    lb[j] = Bs + (w * 32 + j * 8) * 64;
  }
  for (int k0 = 0; k0 < kLen; k0 += 64) {
    __syncthreads();
#pragma unroll
    for (int j = 0; j < 4; ++j) {
      gl_lds16(ga[j] + k0, la[j]);
      gl_lds16(gb[j] + k0, lb[j]);
    }
    __syncthreads();
#pragma unroll
    for (int kk = 0; kk < 2; ++kk) {
      bf16x8 af[4], bff[4];
#pragma unroll
      for (int m = 0; m < 4; ++m) {
        int row = wr * 64 + m * 16 + (lane & 15);
        int c = kk * 4 + (lane >> 4);
        af[m] = *(const bf16x8*)(As + row * 64 + ((c ^ (row & 7)) << 3));
      }
#pragma unroll
      for (int n = 0; n < 4; ++n) {
        int row = wc * 64 + n * 16 + (lane & 15);
        int c = kk * 4 + (lane >> 4);
        bff[n] = *(const bf16x8*)(Bs + row * 64 + ((c ^ (row & 7)) << 3));
      }
#pragma unroll
      for (int m = 0; m < 4; ++m)
#pragma unroll
        for (int n = 0; n < 4; ++n)
          acc[m][n] = __builtin_amdgcn_mfma_f32_16x16x32_bf16(bff[n], af[m], acc[m][n], 0, 0, 0);
    }
  }
}

// -------- GEMM1: xn @ W_in + b_in, fused rope/qkv-scatter/vT/gelu ---------
__global__ __launch_bounds__(256) void gemm1_k(const ushort* __restrict__ A,
    const ushort* __restrict__ Bt, const float* __restrict__ bias,
    const float* __restrict__ sn, const float* __restrict__ cs,
    ushort* __restrict__ qbuf, ushort* __restrict__ kbuf,
    ushort* __restrict__ vt, ushort* __restrict__ comb) {
  __shared__ __align__(16) ushort As[128 * 64];
  __shared__ __align__(16) ushort Bs[128 * 64];
  f32x4 acc[4][4];
  f32x4 z = {0.f, 0.f, 0.f, 0.f};
#pragma unroll
  for (int m = 0; m < 4; ++m)
#pragma unroll
    for (int n = 0; n < 4; ++n) acc[m][n] = z;
  int bid = blockIdx.x;                       // 2688 blocks
  int nb = (bid & 7) * 336 + (bid >> 3);      // bijective XCD swizzle
  int bx = nb % 42, by = nb / 42;
  int mBase = by * 128, nBase = bx * 128;
  gemm_core(A, Bt, 768, 768, mBase, nBase, As, Bs, acc);
  int t = threadIdx.x, lane = t & 63, w = t >> 6, wr = w >> 1, wc = w & 1;
  bool isff = (nBase >= 2304);
  int region = nBase / 768;  // 0=q 1=k 2=v (only valid when !isff)
#pragma unroll
  for (int m = 0; m < 4; ++m) {
    int row = mBase + wr * 64 + m * 16 + (lane & 15);
    int b = row >> 12, s = row & 4095;
#pragma unroll
    for (int n = 0; n < 4; ++n) {
      int col = nBase + wc * 64 + n * 16 + ((lane >> 4) << 2);
      f32x4 v = acc[m][n] + *(const f32x4*)(bias + col);
      if (isff) {
        ushort4 o;
        o.x = f2bfu(gelu_f(v[0]));
        o.y = f2bfu(gelu_f(v[1]));
        o.z = f2bfu(gelu_f(v[2]));
        o.w = f2bfu(gelu_f(v[3]));
        *(ushort4*)(comb + (size_t)row * 3840 + (col - 1536)) = o;
      } else {
        int rem = col - region * 768;
        int h = rem >> 6, d0 = rem & 63;
        if (region == 2) {
          size_t vb = (size_t)((b * 12 + h) * 64 + d0) * 4096 + s;
          vt[vb]           = f2bfu(v[0]);
          vt[vb + 4096]    = f2bfu(v[1]);
          vt[vb + 2*4096]  = f2bfu(v[2]);
          vt[vb + 3*4096]  = f2bfu(v[3]);
        } else {
          f32x4 sv = *(const f32x4*)(sn + (s << 6) + d0);
          f32x4 cv = *(const f32x4*)(cs + (s << 6) + d0);
          float o0 = v[0] * cv[0] - v[1] * sv[0];
          float o1 = v[1] * cv[0] + v[0] * sv[0];
          float o2 = v[2] * cv[2] - v[3] * sv[2];
          float o3 = v[3] * cv[2] + v[2] * sv[2];
          ushort4 o;
          if (region == 0) {
            o.x = f2bfu(o0 * 0.125f); o.y = f2bfu(o1 * 0.125f);
            o.z = f2bfu(o2 * 0.125f); o.w = f2bfu(o3 * 0.125f);
            *(ushort4*)(qbuf + ((size_t)((b * 12 + h) * 4096 + s)) * 64 + d0) = o;
          } else {
            o.x = f2bfu(o0); o.y = f2bfu(o1); o.z = f2bfu(o2); o.w = f2bfu(o3);
            *(ushort4*)(kbuf + ((size_t)((b * 12 + h) * 4096 + s)) * 64 + d0) = o;
          }
        }
      }
    }
  }
}

// -------- GEMM2 split-K=2: comb @ W_out -> fp32 partials ------------------
__global__ __launch_bounds__(256) void gemm2_k(const ushort* __restrict__ A,
    const ushort* __restrict__ Bt, float* __restrict__ p0,
    float* __restrict__ p1) {
  __shared__ __align__(16) ushort As[128 * 64];
  __shared__ __align__(16) ushort Bs[128 * 64];
  f32x4 acc[4][4];
  f32x4 z = {0.f, 0.f, 0.f, 0.f};
#pragma unroll
  for (int m = 0; m < 4; ++m)
#pragma unroll
    for (int n = 0; n < 4; ++n) acc[m][n] = z;
  int bid = blockIdx.x;                      // 768 blocks
  int nb = (bid & 7) * 96 + (bid >> 3);
  int bx = nb % 6; int rest = nb / 6;
  int by = rest & 63, kz = rest >> 6;
  int mBase = by * 128, nBase = bx * 128;
  gemm_core(A + kz * 1920, Bt + kz * 1920, 3840, 1920, mBase, nBase, As, Bs, acc);
  float* p = kz ? p1 : p0;
  int t = threadIdx.x, lane = t & 63, w = t >> 6, wr = w >> 1, wc = w & 1;
#pragma unroll
  for (int m = 0; m < 4; ++m) {
    int row = mBase + wr * 64 + m * 16 + (lane & 15);
#pragma unroll
    for (int n = 0; n < 4; ++n) {
      int col = nBase + wc * 64 + n * 16 + ((lane >> 4) << 2);
      *(f32x4*)(p + (size_t)row * 768 + col) = acc[m][n];
    }
  }
}

// -------- reduce: out = p0 + p1 + bias ------------------------------------
__global__ __launch_bounds__(256) void red_k(const float* __restrict__ p0,
    const float* __restrict__ p1, const float* __restrict__ bias,
    float* __restrict__ out) {
  const int n4 = 8192 * 768 / 4;
  for (int i = blockIdx.x * 256 + threadIdx.x; i < n4; i += gridDim.x * 256) {
    f32x4 a = *(const f32x4*)(p0 + 4 * (size_t)i);
    f32x4 b = *(const f32x4*)(p1 + 4 * (size_t)i);
    f32x4 c = *(const f32x4*)(bias + (4 * i) % 768);
    *(f32x4*)(out + 4 * (size_t)i) = a + b + c;
  }
}

// ---------------- windowed attention (flash-style, window 512) ------------
__global__ __launch_bounds__(256) void attn_k(const ushort* __restrict__ qb,
    const ushort* __restrict__ kb, const ushort* __restrict__ vt,
    ushort* __restrict__ comb) {
  __shared__ __align__(16) ushort Ks[128 * 64];
  __shared__ __align__(16) ushort Vs[64 * 128];
  __shared__ __align__(16) ushort Ps[4][32 * 128];
  int bid = blockIdx.x;                      // 768 blocks
  int nb = (bid & 7) * 96 + (bid >> 3);
  int qt = nb & 31, bh = nb >> 5;
  int t = threadIdx.x, lane = t & 63, w = t >> 6;
  int qlo = qt * 128;
  const size_t base = (size_t)bh * 4096 * 64;
  bf16x8 qa[2][2];
#pragma unroll
  for (int m = 0; m < 2; ++m)
#pragma unroll
    for (int kk = 0; kk < 2; ++kk) {
      int row = qlo + w * 32 + m * 16 + (lane & 15);
      qa[m][kk] = *(const bf16x8*)(qb + base + (size_t)row * 64 + kk * 32 + ((lane >> 4) << 3));
    }
  f32x4 z = {0.f, 0.f, 0.f, 0.f};
  f32x4 o[2][4];
  float m_run[2][4], l_run[2][4];
#pragma unroll
  for (int m = 0; m < 2; ++m)
#pragma unroll
    for (int r = 0; r < 4; ++r) { m_run[m][r] = -1e30f; l_run[m][r] = 0.f; }
#pragma unroll
  for (int m = 0; m < 2; ++m)
#pragma unroll
    for (int df = 0; df < 4; ++df) o[m][df] = z;
  ushort* pw = &Ps[w][0];
  int t0 = qt >= 4 ? qt - 4 : 0;
  for (int kt = t0; kt <= qt; ++kt) {
    int k0 = kt * 128;
    __syncthreads();
#pragma unroll
    for (int j = 0; j < 4; ++j) {
      int ch = t + 256 * j;
      int key = ch >> 3, c = ch & 7;
      *(int4*)(Ks + key * 64 + ((c ^ (key & 7)) << 3)) =
          *(const int4*)(kb + base + (size_t)(k0 + key) * 64 + c * 8);
      int dd = ch >> 4, c2 = ch & 15;
      *(int4*)(Vs + dd * 128 + ((c2 ^ (dd & 15)) << 3)) =
          *(const int4*)(vt + base + (size_t)dd * 4096 + k0 + c2 * 8);
    }
    __syncthreads();
    f32x4 s[2][8];
#pragma unroll
    for (int m = 0; m < 2; ++m)
#pragma unroll
      for (int n = 0; n < 8; ++n) s[m][n] = z;
#pragma unroll
    for (int kk = 0; kk < 2; ++kk) {
      bf16x8 kf[8];
#pragma unroll
      for (int n = 0; n < 8; ++n) {
        int key = n * 16 + (lane & 15);
        int c = kk * 4 + (lane >> 4);
        kf[n] = *(const bf16x8*)(Ks + key * 64 + ((c ^ (key & 7)) << 3));
      }
#pragma unroll
      for (int m = 0; m < 2; ++m)
#pragma unroll
        for (int n = 0; n < 8; ++n)
          s[m][n] = __builtin_amdgcn_mfma_f32_16x16x32_bf16(qa[m][kk], kf[n], s[m][n], 0, 0, 0);
    }
#pragma unroll
    for (int m = 0; m < 2; ++m) {
#pragma unroll
      for (int r = 0; r < 4; ++r) {
        int qrow = qlo + w * 32 + m * 16 + ((lane >> 4) << 2) + r;
        float mx = -3e38f;
#pragma unroll
        for (int n = 0; n < 8; ++n) {
          int krow = k0 + n * 16 + (lane & 15);
          if ((unsigned)(qrow - krow) >= 512u) s[m][n][r] = -3e38f;
          mx = fmaxf(mx, s[m][n][r]);
        }
        mx = fmaxf(mx, __shfl_xor(mx, 1, 64));
        mx = fmaxf(mx, __shfl_xor(mx, 2, 64));
        mx = fmaxf(mx, __shfl_xor(mx, 4, 64));
        mx = fmaxf(mx, __shfl_xor(mx, 8, 64));
        float mo = m_run[m][r];
        float mn = fmaxf(mo, mx);
        float sc = exp2f((mo - mn) * LOG2E);
        m_run[m][r] = mn;
        l_run[m][r] *= sc;
#pragma unroll
        for (int df = 0; df < 4; ++df) o[m][df][r] *= sc;
        float ls = 0.f;
#pragma unroll
        for (int n = 0; n < 8; ++n) {
          float p = exp2f((s[m][n][r] - mn) * LOG2E);
          s[m][n][r] = p;
          ls += p;
        }
        ls += __shfl_xor(ls, 1, 64);
        ls += __shfl_xor(ls, 2, 64);
        ls += __shfl_xor(ls, 4, 64);
        ls += __shfl_xor(ls, 8, 64);
        l_run[m][r] += ls;
      }
    }
#pragma unroll
    for (int m = 0; m < 2; ++m)
#pragma unroll
      for (int n = 0; n < 8; ++n)
#pragma unroll
        for (int r = 0; r < 4; ++r) {
          int prow = m * 16 + ((lane >> 4) << 2) + r;
          int pcol = n * 16 + (lane & 15);
          int c = pcol >> 3;
          pw[prow * 128 + ((c ^ (prow & 7)) << 3) + (pcol & 7)] = f2bfu(s[m][n][r]);
        }
    __syncthreads();
#pragma unroll
    for (int kk2 = 0; kk2 < 4; ++kk2) {
      bf16x8 pa[2];
#pragma unroll
      for (int m = 0; m < 2; ++m) {
        int prow = m * 16 + (lane & 15);
        int c = kk2 * 4 + (lane >> 4);
        pa[m] = *(const bf16x8*)(pw + prow * 128 + ((c ^ (prow & 7)) << 3));
      }
#pragma unroll
      for (int df = 0; df < 4; ++df) {
        int dim = df * 16 + (lane & 15);
        int c = kk2 * 4 + (lane >> 4);
        bf16x8 vf = *(const bf16x8*)(Vs + dim * 128 + ((c ^ (dim & 15)) << 3));
#pragma unroll
        for (int m = 0; m < 2; ++m)
          o[m][df] = __builtin_amdgcn_mfma_f32_16x16x32_bf16(pa[m], vf, o[m][df], 0, 0, 0);
      }
    }
  }
  int b = bh / 12, h = bh - (bh / 12) * 12;
#pragma unroll
  for (int m = 0; m < 2; ++m)
#pragma unroll
    for (int df = 0; df < 4; ++df)
#pragma unroll
      for (int r = 0; r < 4; ++r) {
        int row = qlo + w * 32 + m * 16 + ((lane >> 4) << 2) + r;
        int dim = df * 16 + (lane & 15);
        float val = o[m][df][r] / l_run[m][r];
        comb[(size_t)(b * 4096 + row) * 3840 + h * 64 + dim] = f2bfu(val);
      }
}

extern "C" void kernel_launch(void* const* d_in, const int* in_sizes, int n_in,
                              void* d_out, int out_size, void* d_ws, size_t ws_size,
                              hipStream_t stream) {
  (void)in_sizes; (void)n_in; (void)out_size; (void)ws_size;
  const float* x      = (const float*)d_in[0];
  const float* sin_t  = (const float*)d_in[1];
  const float* cos_t  = (const float*)d_in[2];
  const float* w_norm = (const float*)d_in[3];
  const float* W_in   = (const float*)d_in[4];
  const float* b_in   = (const float*)d_in[5];
  const float* W_out  = (const float*)d_in[6];
  const float* b_out  = (const float*)d_in[7];
  float* out = (float*)d_out;

  const size_t XN_E  = (size_t)8192 * 768;     // == QKV_E
  ushort* xn      = (ushort*)d_ws;
  ushort* qbuf    = xn + XN_E;
  ushort* kbuf    = qbuf + QKV_E;
  ushort* vt      = kbuf + QKV_E;
  ushort* w_in_t  = vt + QKV_E;
  ushort* w_out_t = w_in_t + (size_t)5376 * 768;
  ushort* comb    = w_out_t + (size_t)768 * 3840;
  // fp32 partials alias xn/qbuf (p0) and kbuf/vt (p1) — dead by gemm2 time
  float* p0 = (float*)d_ws;
  float* p1 = p0 + (size_t)8192 * 768;

  rmsnorm_k<<<dim3(8192), dim3(256), 0, stream>>>(x, w_norm, xn);
  tcvt_k<<<dim3(5376 / 32, 768 / 32), dim3(256), 0, stream>>>(W_in, w_in_t, 768, 5376);
  tcvt_k<<<dim3(768 / 32, 3840 / 32), dim3(256), 0, stream>>>(W_out, w_out_t, 3840, 768);
  gemm1_k<<<dim3(2688), dim3(256), 0, stream>>>(xn, w_in_t, b_in, sin_t, cos_t,
                                                qbuf, kbuf, vt, comb);
  attn_k<<<dim3(768), dim3(256), 0, stream>>>(qbuf, kbuf, vt, comb);
  gemm2_k<<<dim3(768), dim3(256), 0, stream>>>(comb, w_out_t, p0, p1);
  red_k<<<dim3(2048), dim3(256), 0, stream>>>(p0, p1, b_out, out);
}